// Round 2
// baseline (317.529 us; speedup 1.0000x reference)
//
#include <hip/hip_runtime.h>
#include <hip/hip_bf16.h>

// CorrelationLayer: out[b,(dy+4)*9+(dx+4),h,w] = sum_c f1[b,c,h,w]*f2[b,c,(h-dy)&63,(w-dx)&127]
// B=8 C=512 H=64 W=128, 81 displacements.
//
// Design (R1, MFMA bf16):
//  - grid 256 = 8 batch * 4 htiles(16) * 8 wstrips(16); b = blockIdx&7 -> XCD-pinned batch.
//  - block 512 thr = 8 waves; wave owns 2 h-rows, all 9 dy, 2 N-tiles -> acc 144 VGPR.
//  - per (h,dy): D[p][q] = mfma_16x16x32_bf16(A=f1[c, h, w0+p], B=f2[c, h-dy, cols]),
//    two B col-windows: w0-4..w0+11 (dx = p-q+4) and w0+12..w0+27 (dx = p-q-12).
//  - f2 halo (24 rows x 32 cols) staged fp32->bf16 in LDS [row][wt][w][72c-pad] (110KB),
//    c-contiguous so a B fragment is one ds_read_b128. f1 fragments direct from global.
//  - K staged in 8 chunks of 64 (2 MFMA k-steps per barrier pair).

typedef short  bf16x8  __attribute__((ext_vector_type(8)));
typedef short  short4v __attribute__((ext_vector_type(4)));
typedef float  f32x4   __attribute__((ext_vector_type(4)));

#define NB 8
#define NC 512
#define NH 64
#define NW 128
#define HW (NH * NW)
#define TH 16
#define TW 16
#define CC 64                 // channels per LDS stage (2 MFMA k-steps)
#define NSTAGE (NC / CC)      // 8
#define LROW 24               // f2 halo rows per tile
#define LCP  72               // padded channel count (shorts) per (row,wt,w)
#define LDS_SHORTS (LROW * 2 * 16 * LCP)   // 55296 shorts = 110592 B

__device__ __forceinline__ short f2bf(float x) {
  union { __hip_bfloat16 h; short s; } u;
  u.h = __float2bfloat16(x);
  return u.s;
}

__global__ __launch_bounds__(512, 2)
void corr_mfma(const float* __restrict__ f1, const float* __restrict__ f2,
               float* __restrict__ out) {
  __shared__ short lds[LDS_SHORTS];

  const int t    = threadIdx.x;
  const int b    = blockIdx.x & 7;        // XCD swizzle: batch == XCD
  const int tile = blockIdx.x >> 3;       // 0..31
  const int h0   = (tile >> 3) * TH;      // 0,16,32,48
  const int w0   = (tile & 7) * TW;       // 0..112

  const int wv = t >> 6;                  // wave 0..7
  const int l  = t & 63;
  const int lg = l >> 4;                  // 0..3
  const int lw = l & 15;                  // 0..15

  // staging decomposition: thread -> (w in tile-col, c-quad, row-phase)
  const int sw  = t & 15;                 // col within 16-col subtile
  const int scq = (t >> 4) & 7;           // c-quad 0..7 (also +8 via cc loop)
  const int srb = t >> 7;                 // 0..3 row phase

  const float* f1b = f1 + b * NC * HW;
  const float* f2b = f2 + b * NC * HW;

  f32x4 acc[2][9][2];
#pragma unroll
  for (int hh = 0; hh < 2; ++hh)
#pragma unroll
    for (int d = 0; d < 9; ++d)
#pragma unroll
      for (int wt = 0; wt < 2; ++wt)
        acc[hh][d][wt] = (f32x4){0.f, 0.f, 0.f, 0.f};

  const int hA = h0 + 2 * wv;             // wave's first h row

  for (int st = 0; st < NSTAGE; ++st) {
    const int c0 = st * CC;

    // ---- A fragments: issue global loads early (no LDS; latency overlaps staging)
    float a_raw[2][2][8];
#pragma unroll
    for (int kk = 0; kk < 2; ++kk)
#pragma unroll
      for (int hh = 0; hh < 2; ++hh) {
        const float* s = f1b + (c0 + kk * 32 + 8 * lg) * HW + (hA + hh) * NW + (w0 + lw);
#pragma unroll
        for (int e = 0; e < 8; ++e)
          a_raw[kk][hh][e] = s[e * HW];
      }

    __syncthreads();   // previous compute finished reading LDS

    // ---- stage f2 chunk: 24 rows x 2 subtiles x 16 cols x 64 c, fp32->bf16
#pragma unroll
    for (int wt = 0; wt < 2; ++wt) {
      const int wg = (w0 + wt * 16 - 4 + sw) & (NW - 1);
#pragma unroll
      for (int rr = 0; rr < 6; ++rr) {
        const int row = rr * 4 + srb;                    // 0..23
        const int h2  = (h0 - 4 + row) & (NH - 1);
        const float* src = f2b + c0 * HW + h2 * NW + wg;
        short* dst = lds + (row * 2 + wt) * (16 * LCP) + sw * LCP;
#pragma unroll
        for (int cc = 0; cc < 2; ++cc) {
          const int cb = scq * 4 + cc * 32;              // covers c 0..63 in quads
          float x0 = src[(cb + 0) * HW];
          float x1 = src[(cb + 1) * HW];
          float x2 = src[(cb + 2) * HW];
          float x3 = src[(cb + 3) * HW];
          short4v v = { f2bf(x0), f2bf(x1), f2bf(x2), f2bf(x3) };
          *reinterpret_cast<short4v*>(dst + cb) = v;     // ds_write_b64, 8B aligned
        }
      }
    }

    // pack A while staging stores drain
    bf16x8 afr[2][2];
#pragma unroll
    for (int kk = 0; kk < 2; ++kk)
#pragma unroll
      for (int hh = 0; hh < 2; ++hh)
#pragma unroll
        for (int e = 0; e < 8; ++e)
          afr[kk][hh][e] = f2bf(a_raw[kk][hh][e]);

    __syncthreads();   // LDS chunk ready

    // ---- compute: per k-step, walk the 10 f2 rows this wave needs
#pragma unroll
    for (int kk = 0; kk < 2; ++kk) {
#pragma unroll
      for (int ro = 0; ro < 10; ++ro) {
        const int row = 2 * wv + ro;                     // lds row = global (h-dy)-(h0-4)
#pragma unroll
        for (int wt = 0; wt < 2; ++wt) {
          const bf16x8 bfr = *reinterpret_cast<const bf16x8*>(
              lds + (row * 2 + wt) * (16 * LCP) + lw * LCP + kk * 32 + 8 * lg);
          // row = 2wv+hh+8-dyi  =>  dyi = hh + 8 - ro
          if (ro <= 8)
            acc[0][8 - ro][wt] = __builtin_amdgcn_mfma_f32_16x16x32_bf16(
                afr[kk][0], bfr, acc[0][8 - ro][wt], 0, 0, 0);
          if (ro >= 1)
            acc[1][9 - ro][wt] = __builtin_amdgcn_mfma_f32_16x16x32_bf16(
                afr[kk][1], bfr, acc[1][9 - ro][wt], 0, 0, 0);
        }
      }
    }
  }

  // ---- epilogue: D[p=4*lg+r][q=lw]; wt0: dx = p-q+4, wt1: dx = p-q-12
#pragma unroll
  for (int hh = 0; hh < 2; ++hh) {
    const int h = hA + hh;
#pragma unroll
    for (int d = 0; d < 9; ++d) {
#pragma unroll
      for (int wt = 0; wt < 2; ++wt) {
#pragma unroll
        for (int r = 0; r < 4; ++r) {
          const int p   = 4 * lg + r;
          const int dxi = p - lw + (wt == 0 ? 8 : -8);   // dx+4
          if (dxi >= 0 && dxi <= 8) {
            out[((b * 81 + d * 9 + dxi) * NH + h) * NW + (w0 + p)] = acc[hh][d][wt][r];
          }
        }
      }
    }
  }
}

extern "C" void kernel_launch(void* const* d_in, const int* in_sizes, int n_in,
                              void* d_out, int out_size, void* d_ws, size_t ws_size,
                              hipStream_t stream) {
  const float* f1 = (const float*)d_in[0];
  const float* f2 = (const float*)d_in[1];
  float* out = (float*)d_out;
  corr_mfma<<<dim3(256), dim3(512), 0, stream>>>(f1, f2, out);
}